// Round 1
// baseline (271.504 us; speedup 1.0000x reference)
//
#include <hip/hip_runtime.h>
#include <hip/hip_bf16.h>
#include <stdint.h>

#define E_EDGES 100000
#define IN_F    256
#define HID     128
#define KNB     16

typedef short bf16x8 __attribute__((ext_vector_type(8)));
typedef float f32x4  __attribute__((ext_vector_type(4)));

__device__ __forceinline__ unsigned short f2bf(float f) {
    union { float f; unsigned u; } v; v.f = f;
    unsigned u = v.u;
    u += 0x7fffu + ((u >> 16) & 1u);   // round-to-nearest-even
    return (unsigned short)(u >> 16);
}

// W [256][128] fp32  ->  Wt [128][256] bf16 (transposed so B-frags are 16B-contiguous)
__global__ void conv_w_kernel(const float* __restrict__ W, unsigned short* __restrict__ Wt) {
    int t = blockIdx.x * blockDim.x + threadIdx.x;   // 0..32767
    int n = t & (HID - 1);
    int k = t >> 7;
    Wt[(size_t)n * IN_F + k] = f2bf(W[(size_t)k * HID + n]);
}

// t = A @ W + b, stored bf16 [E][128].
// Block = 256 thr = 4 waves; block tile 32 rows x 128 cols; wave tile 32x32 (2x2 MFMA accs).
// No LDS: A-frags loaded fp32 (L1 reuse across the 4 waves), converted in-reg;
// B-frags are 16B contiguous loads from Wt (64 KB, L1/L2-hot).
__launch_bounds__(256)
__global__ void gemm_t_kernel(const float* __restrict__ A,
                              const unsigned short* __restrict__ Wt,
                              const float* __restrict__ bias,
                              unsigned short* __restrict__ T) {
    const int wave = threadIdx.x >> 6;   // 0..3
    const int lane = threadIdx.x & 63;
    const int l15  = lane & 15;
    const int quad = lane >> 4;          // 0..3
    const int row0 = blockIdx.x * 32;
    const int col0 = wave * 32;

    f32x4 acc[2][2] = {};

    for (int k0 = 0; k0 < IN_F; k0 += 32) {
        bf16x8 afrag[2], bfrag[2];
        // A fragments: A[m = row0 + rt*16 + l15][k = k0 + quad*8 + j], fp32 -> bf16
        #pragma unroll
        for (int rt = 0; rt < 2; ++rt) {
            const float* ap = A + (size_t)(row0 + rt * 16 + l15) * IN_F + k0 + quad * 8;
            float4 lo = *(const float4*)ap;
            float4 hi = *(const float4*)(ap + 4);
            bf16x8 f;
            f[0] = (short)f2bf(lo.x); f[1] = (short)f2bf(lo.y);
            f[2] = (short)f2bf(lo.z); f[3] = (short)f2bf(lo.w);
            f[4] = (short)f2bf(hi.x); f[5] = (short)f2bf(hi.y);
            f[6] = (short)f2bf(hi.z); f[7] = (short)f2bf(hi.w);
            afrag[rt] = f;
        }
        // B fragments: B[k][n] with n = col0 + ct*16 + l15, k = k0 + quad*8 + j
        #pragma unroll
        for (int ct = 0; ct < 2; ++ct) {
            const unsigned short* bp =
                Wt + (size_t)(col0 + ct * 16 + l15) * IN_F + k0 + quad * 8;
            bfrag[ct] = *(const bf16x8*)bp;   // 16 B contiguous
        }
        #pragma unroll
        for (int rt = 0; rt < 2; ++rt)
            #pragma unroll
            for (int ct = 0; ct < 2; ++ct)
                acc[rt][ct] = __builtin_amdgcn_mfma_f32_16x16x32_bf16(
                    afrag[rt], bfrag[ct], acc[rt][ct], 0, 0, 0);
    }

    // Epilogue: +bias, bf16 store. C/D layout: col = lane&15, row = quad*4 + reg.
    #pragma unroll
    for (int rt = 0; rt < 2; ++rt) {
        #pragma unroll
        for (int ct = 0; ct < 2; ++ct) {
            const int col = col0 + ct * 16 + l15;
            const float bv = bias[col];
            #pragma unroll
            for (int i = 0; i < 4; ++i) {
                const int row = row0 + rt * 16 + quad * 4 + i;
                T[(size_t)row * HID + col] = f2bf(acc[rt][ct][i] + bv);
            }
        }
    }
}

// out[i] = t[i] + sum_k t[nbr[i][k]]  (fp32 accumulate from bf16 t)
// Block = 256 thr = 16 edges; 16 lanes/edge, 8 feats/lane via uint4 (8 bf16).
__launch_bounds__(256)
__global__ void gather_sum_kernel(const unsigned short* __restrict__ T,
                                  const int* __restrict__ nbr,
                                  float* __restrict__ out) {
    __shared__ int sidx[256];
    const int tid   = threadIdx.x;
    const int edge0 = blockIdx.x * 16;
    sidx[tid] = nbr[(size_t)edge0 * KNB + tid];   // 16 edges x 16 nbrs
    __syncthreads();

    const int el   = tid >> 4;        // local edge 0..15
    const int lane = tid & 15;        // feature group: feats [lane*8, lane*8+8)
    const int edge = edge0 + el;

    float acc[8];
    {   // self row initializes acc
        uint4 v = *(const uint4*)(T + (size_t)edge * HID + lane * 8);
        unsigned w[4] = { v.x, v.y, v.z, v.w };
        union { unsigned u; float f; } c;
        #pragma unroll
        for (int j = 0; j < 4; ++j) {
            c.u = w[j] << 16;          acc[2 * j]     = c.f;
            c.u = w[j] & 0xffff0000u;  acc[2 * j + 1] = c.f;
        }
    }
    #pragma unroll
    for (int k = 0; k < KNB; ++k) {
        const int n = sidx[el * KNB + k];
        uint4 v = *(const uint4*)(T + (size_t)n * HID + lane * 8);
        unsigned w[4] = { v.x, v.y, v.z, v.w };
        union { unsigned u; float f; } c;
        #pragma unroll
        for (int j = 0; j < 4; ++j) {
            c.u = w[j] << 16;          acc[2 * j]     += c.f;
            c.u = w[j] & 0xffff0000u;  acc[2 * j + 1] += c.f;
        }
    }

    float* op = out + (size_t)edge * HID + lane * 8;
    float4 o0 = { acc[0], acc[1], acc[2], acc[3] };
    float4 o1 = { acc[4], acc[5], acc[6], acc[7] };
    *(float4*)op       = o0;
    *(float4*)(op + 4) = o1;
}

extern "C" void kernel_launch(void* const* d_in, const int* in_sizes, int n_in,
                              void* d_out, int out_size, void* d_ws, size_t ws_size,
                              hipStream_t stream) {
    const float* edge_feats = (const float*)d_in[0];   // [E, 256] fp32
    const int*   neighbors  = (const int*)d_in[1];     // [E, 16] int32
    const float* W          = (const float*)d_in[2];   // [256, 128] fp32
    const float* b          = (const float*)d_in[3];   // [128] fp32
    float*       out        = (float*)d_out;           // [E, 128] fp32

    unsigned short* Wt = (unsigned short*)d_ws;                      // 64 KB
    unsigned short* T  = (unsigned short*)d_ws + (size_t)IN_F * HID; // 25.6 MB, 64KB-offset (16B aligned)

    conv_w_kernel<<<(IN_F * HID) / 256, 256, 0, stream>>>(W, Wt);
    gemm_t_kernel<<<E_EDGES / 32, 256, 0, stream>>>(edge_feats, Wt, b, T);
    gather_sum_kernel<<<E_EDGES / 16, 256, 0, stream>>>(T, neighbors, out);
}

// Round 2
// 268.383 us; speedup vs baseline: 1.0116x; 1.0116x over previous
//
#include <hip/hip_runtime.h>
#include <hip/hip_bf16.h>
#include <stdint.h>

#define E_EDGES 100000
#define IN_F    256
#define HID     128
#define KNB     16

typedef short bf16x8 __attribute__((ext_vector_type(8)));
typedef float f32x4  __attribute__((ext_vector_type(4)));

__device__ __forceinline__ unsigned short f2bf(float f) {
    union { float f; unsigned u; } v; v.f = f;
    unsigned u = v.u;
    u += 0x7fffu + ((u >> 16) & 1u);   // round-to-nearest-even
    return (unsigned short)(u >> 16);
}

// W [256][128] fp32  ->  Wt [128][256] bf16 (transposed so B-frags are 16B-contiguous)
__global__ void conv_w_kernel(const float* __restrict__ W, unsigned short* __restrict__ Wt) {
    int t = blockIdx.x * blockDim.x + threadIdx.x;   // 0..32767
    int n = t & (HID - 1);
    int k = t >> 7;
    Wt[(size_t)n * IN_F + k] = f2bf(W[(size_t)k * HID + n]);
}

// t = A @ W + b, stored bf16 [E][128].
// Block = 256 thr = 4 waves; block tile 64 rows x 128 cols; wave tile 16 rows x 128 cols.
// Full-K A prefetch (16 float4/lane in flight) kills the per-k-step latency stall
// that made R1 latency-bound (VGPR=36, MfmaUtil 2.7%). B-frags from global (L1-hot,
// 64 KB Wt shared by all waves), 8 MFMAs per k-step.
__launch_bounds__(256)
__global__ void gemm_t_kernel(const float* __restrict__ A,
                              const unsigned short* __restrict__ Wt,
                              const float* __restrict__ bias,
                              unsigned short* __restrict__ T) {
    const int wave = threadIdx.x >> 6;   // 0..3
    const int lane = threadIdx.x & 63;
    const int l15  = lane & 15;
    const int quad = lane >> 4;          // 0..3
    const int rowbase = blockIdx.x * 64 + wave * 16;

    // A-operand row for this lane (A[m = l15][k = quad*8 + j] layout)
    int arow = rowbase + l15;
    if (arow >= E_EDGES) arow = E_EDGES - 1;   // clamp; stores are guarded below

    // Full-K prefetch: all 256 k-values for this lane's row slice.
    // k index for chunk k0 (0..7): k = k0*32 + quad*8 + j, j in [0,8)
    const float* ap = A + (size_t)arow * IN_F + quad * 8;
    float4 apre[16];
    #pragma unroll
    for (int k0 = 0; k0 < 8; ++k0) {
        apre[2 * k0]     = *(const float4*)(ap + k0 * 32);
        apre[2 * k0 + 1] = *(const float4*)(ap + k0 * 32 + 4);
    }

    f32x4 acc[8] = {};

    #pragma unroll
    for (int k0 = 0; k0 < 8; ++k0) {
        // B fragments for all 8 col-tiles: B[k = k0*32 + quad*8 + j][n = ct*16 + l15]
        bf16x8 bfrag[8];
        #pragma unroll
        for (int ct = 0; ct < 8; ++ct)
            bfrag[ct] = *(const bf16x8*)(Wt + (size_t)(ct * 16 + l15) * IN_F
                                            + k0 * 32 + quad * 8);
        // convert this k-chunk of A to bf16
        float4 lo = apre[2 * k0], hi = apre[2 * k0 + 1];
        bf16x8 af;
        af[0] = (short)f2bf(lo.x); af[1] = (short)f2bf(lo.y);
        af[2] = (short)f2bf(lo.z); af[3] = (short)f2bf(lo.w);
        af[4] = (short)f2bf(hi.x); af[5] = (short)f2bf(hi.y);
        af[6] = (short)f2bf(hi.z); af[7] = (short)f2bf(hi.w);
        #pragma unroll
        for (int ct = 0; ct < 8; ++ct)
            acc[ct] = __builtin_amdgcn_mfma_f32_16x16x32_bf16(af, bfrag[ct], acc[ct], 0, 0, 0);
    }

    // Epilogue: +bias, bf16 store. C/D layout: col = l15, row = quad*4 + reg.
    #pragma unroll
    for (int ct = 0; ct < 8; ++ct) {
        const int col = ct * 16 + l15;
        const float bv = bias[col];
        #pragma unroll
        for (int i = 0; i < 4; ++i) {
            const int row = rowbase + quad * 4 + i;
            if (row < E_EDGES)
                T[(size_t)row * HID + col] = f2bf(acc[ct][i] + bv);
        }
    }
}

// out[i] = t[i] + sum_k t[nbr[i][k]]  (fp32 accumulate from bf16 t)
// Block = 256 thr = 16 edges; 16 lanes/edge, 8 feats/lane via uint4 (8 bf16).
__launch_bounds__(256)
__global__ void gather_sum_kernel(const unsigned short* __restrict__ T,
                                  const int* __restrict__ nbr,
                                  float* __restrict__ out) {
    __shared__ int sidx[256];
    const int tid   = threadIdx.x;
    const int edge0 = blockIdx.x * 16;
    sidx[tid] = nbr[(size_t)edge0 * KNB + tid];   // 16 edges x 16 nbrs
    __syncthreads();

    const int el   = tid >> 4;        // local edge 0..15
    const int lane = tid & 15;        // feature group: feats [lane*8, lane*8+8)
    const int edge = edge0 + el;

    float acc[8];
    {   // self row initializes acc
        uint4 v = *(const uint4*)(T + (size_t)edge * HID + lane * 8);
        unsigned w[4] = { v.x, v.y, v.z, v.w };
        union { unsigned u; float f; } c;
        #pragma unroll
        for (int j = 0; j < 4; ++j) {
            c.u = w[j] << 16;          acc[2 * j]     = c.f;
            c.u = w[j] & 0xffff0000u;  acc[2 * j + 1] = c.f;
        }
    }
    #pragma unroll
    for (int k = 0; k < KNB; ++k) {
        const int n = sidx[el * KNB + k];
        uint4 v = *(const uint4*)(T + (size_t)n * HID + lane * 8);
        unsigned w[4] = { v.x, v.y, v.z, v.w };
        union { unsigned u; float f; } c;
        #pragma unroll
        for (int j = 0; j < 4; ++j) {
            c.u = w[j] << 16;          acc[2 * j]     += c.f;
            c.u = w[j] & 0xffff0000u;  acc[2 * j + 1] += c.f;
        }
    }

    float* op = out + (size_t)edge * HID + lane * 8;
    float4 o0 = { acc[0], acc[1], acc[2], acc[3] };
    float4 o1 = { acc[4], acc[5], acc[6], acc[7] };
    *(float4*)op       = o0;
    *(float4*)(op + 4) = o1;
}

extern "C" void kernel_launch(void* const* d_in, const int* in_sizes, int n_in,
                              void* d_out, int out_size, void* d_ws, size_t ws_size,
                              hipStream_t stream) {
    const float* edge_feats = (const float*)d_in[0];   // [E, 256] fp32
    const int*   neighbors  = (const int*)d_in[1];     // [E, 16] int32
    const float* W          = (const float*)d_in[2];   // [256, 128] fp32
    const float* b          = (const float*)d_in[3];   // [128] fp32
    float*       out        = (float*)d_out;           // [E, 128] fp32

    unsigned short* Wt = (unsigned short*)d_ws;                      // 64 KB
    unsigned short* T  = (unsigned short*)d_ws + (size_t)IN_F * HID; // 25.6 MB

    conv_w_kernel<<<(IN_F * HID) / 256, 256, 0, stream>>>(W, Wt);
    gemm_t_kernel<<<(E_EDGES + 63) / 64, 256, 0, stream>>>(edge_feats, Wt, b, T);
    gather_sum_kernel<<<E_EDGES / 16, 256, 0, stream>>>(T, neighbors, out);
}

// Round 3
// 264.271 us; speedup vs baseline: 1.0274x; 1.0156x over previous
//
#include <hip/hip_runtime.h>
#include <hip/hip_bf16.h>
#include <stdint.h>

#define E_EDGES 100000
#define IN_F    256
#define HID     128
#define KNB     16

typedef short bf16x8 __attribute__((ext_vector_type(8)));
typedef float f32x4  __attribute__((ext_vector_type(4)));

__device__ __forceinline__ unsigned short f2bf(float f) {
    union { float f; unsigned u; } v; v.f = f;
    unsigned u = v.u;
    u += 0x7fffu + ((u >> 16) & 1u);   // round-to-nearest-even
    return (unsigned short)(u >> 16);
}

// W [256][128] fp32  ->  Wt [128][256] bf16 (transposed: [n][k])
__global__ void conv_w_kernel(const float* __restrict__ W, unsigned short* __restrict__ Wt) {
    int t = blockIdx.x * blockDim.x + threadIdx.x;   // 0..32767
    int n = t & (HID - 1);
    int k = t >> 7;
    Wt[(size_t)n * IN_F + k] = f2bf(W[(size_t)k * HID + n]);
}

// A fp32 [E*256] -> A_bf bf16 (stored in d_out's memory; dead before gather writes).
// Pure streaming: 8 elems/thread, float4 in, uint4 out. 12500 blocks x 256 thr.
__launch_bounds__(256)
__global__ void conv_a_kernel(const float* __restrict__ A, unsigned short* __restrict__ Abf) {
    size_t i = ((size_t)blockIdx.x * 256 + threadIdx.x) * 8;
    float4 lo = *(const float4*)(A + i);
    float4 hi = *(const float4*)(A + i + 4);
    uint4 o;
    o.x = (unsigned)f2bf(lo.x) | ((unsigned)f2bf(lo.y) << 16);
    o.y = (unsigned)f2bf(lo.z) | ((unsigned)f2bf(lo.w) << 16);
    o.z = (unsigned)f2bf(hi.x) | ((unsigned)f2bf(hi.y) << 16);
    o.w = (unsigned)f2bf(hi.z) | ((unsigned)f2bf(hi.w) << 16);
    *(uint4*)(Abf + i) = o;
}

// T = A_bf @ W + b, stored bf16 [E][128].
// Block = 256 thr = 4 waves; block tile 64 rows x 128 cols; wave = 16 rows x 128 cols.
// Wt staged ONCE per block into LDS in MFMA-fragment order: frag (k0,ct) for lane L
// lives at granule (k0*8+ct)*64 + L  ->  K-loop B-reads are stride-1 ds_read_b128,
// conflict-free. A-prefetch = 8 x bf16x8 per lane (32 VGPR), full K in flight.
__launch_bounds__(256)
__global__ void gemm_t_kernel(const unsigned short* __restrict__ Abf,
                              const unsigned short* __restrict__ Wt,
                              const float* __restrict__ bias,
                              unsigned short* __restrict__ T) {
    __shared__ unsigned short Bs[32768];   // 64 KB
    const int tid = threadIdx.x;

    // Stage Wt -> LDS, swizzled to fragment order.
    // Source uint4 index e over Wt[128][256]: n=e>>5, k8=e&31 (k=k8*8).
    // Frag coords: k0=k8>>2, quad=k8&3, ct=n>>4, l15=n&15, lane=quad*16+l15.
    #pragma unroll
    for (int it = 0; it < 16; ++it) {
        int e    = it * 256 + tid;
        int n    = e >> 5;
        int k8   = e & 31;
        int dst  = ((k8 >> 2) * 8 + (n >> 4)) * 64 + (k8 & 3) * 16 + (n & 15);
        uint4 v = *(const uint4*)(Wt + (size_t)e * 8);
        *(uint4*)(Bs + (size_t)dst * 8) = v;
    }

    const int wave = tid >> 6;
    const int lane = tid & 63;
    const int l15  = lane & 15;
    const int quad = lane >> 4;
    const int rowbase = blockIdx.x * 64 + wave * 16;
    int arow = rowbase + l15;
    if (arow >= E_EDGES) arow = E_EDGES - 1;   // clamp; stores guarded below

    // Full-K A prefetch: 8 x 16B loads, issued before the barrier so they
    // overlap the staging drain.
    const unsigned short* ap = Abf + (size_t)arow * IN_F + quad * 8;
    bf16x8 apre[8];
    #pragma unroll
    for (int k0 = 0; k0 < 8; ++k0)
        apre[k0] = *(const bf16x8*)(ap + k0 * 32);

    __syncthreads();

    f32x4 acc[8] = {};
    #pragma unroll
    for (int k0 = 0; k0 < 8; ++k0) {
        #pragma unroll
        for (int ct = 0; ct < 8; ++ct) {
            bf16x8 bf = *(const bf16x8*)(Bs + ((size_t)((k0 * 8 + ct) * 64 + lane)) * 8);
            acc[ct] = __builtin_amdgcn_mfma_f32_16x16x32_bf16(apre[k0], bf, acc[ct], 0, 0, 0);
        }
    }

    // Epilogue: +bias, bf16 store. C/D layout: col = l15, row = quad*4 + reg.
    #pragma unroll
    for (int ct = 0; ct < 8; ++ct) {
        const int col = ct * 16 + l15;
        const float bv = bias[col];
        #pragma unroll
        for (int i = 0; i < 4; ++i) {
            const int row = rowbase + quad * 4 + i;
            if (row < E_EDGES)
                T[(size_t)row * HID + col] = f2bf(acc[ct][i] + bv);
        }
    }
}

// out[i] = t[i] + sum_k t[nbr[i][k]]  (fp32 accumulate from bf16 t)
// Block = 256 thr = 16 edges; 16 lanes/edge, 8 feats/lane via uint4 (8 bf16).
__launch_bounds__(256)
__global__ void gather_sum_kernel(const unsigned short* __restrict__ T,
                                  const int* __restrict__ nbr,
                                  float* __restrict__ out) {
    __shared__ int sidx[256];
    const int tid   = threadIdx.x;
    const int edge0 = blockIdx.x * 16;
    sidx[tid] = nbr[(size_t)edge0 * KNB + tid];   // 16 edges x 16 nbrs
    __syncthreads();

    const int el   = tid >> 4;        // local edge 0..15
    const int lane = tid & 15;        // feature group: feats [lane*8, lane*8+8)
    const int edge = edge0 + el;

    float acc[8];
    {   // self row initializes acc
        uint4 v = *(const uint4*)(T + (size_t)edge * HID + lane * 8);
        unsigned w[4] = { v.x, v.y, v.z, v.w };
        union { unsigned u; float f; } c;
        #pragma unroll
        for (int j = 0; j < 4; ++j) {
            c.u = w[j] << 16;          acc[2 * j]     = c.f;
            c.u = w[j] & 0xffff0000u;  acc[2 * j + 1] = c.f;
        }
    }
    #pragma unroll
    for (int k = 0; k < KNB; ++k) {
        const int n = sidx[el * KNB + k];
        uint4 v = *(const uint4*)(T + (size_t)n * HID + lane * 8);
        unsigned w[4] = { v.x, v.y, v.z, v.w };
        union { unsigned u; float f; } c;
        #pragma unroll
        for (int j = 0; j < 4; ++j) {
            c.u = w[j] << 16;          acc[2 * j]     += c.f;
            c.u = w[j] & 0xffff0000u;  acc[2 * j + 1] += c.f;
        }
    }

    float* op = out + (size_t)edge * HID + lane * 8;
    float4 o0 = { acc[0], acc[1], acc[2], acc[3] };
    float4 o1 = { acc[4], acc[5], acc[6], acc[7] };
    *(float4*)op       = o0;
    *(float4*)(op + 4) = o1;
}

extern "C" void kernel_launch(void* const* d_in, const int* in_sizes, int n_in,
                              void* d_out, int out_size, void* d_ws, size_t ws_size,
                              hipStream_t stream) {
    const float* edge_feats = (const float*)d_in[0];   // [E, 256] fp32
    const int*   neighbors  = (const int*)d_in[1];     // [E, 16] int32
    const float* W          = (const float*)d_in[2];   // [256, 128] fp32
    const float* b          = (const float*)d_in[3];   // [128] fp32
    float*       out        = (float*)d_out;           // [E, 128] fp32

    unsigned short* Wt  = (unsigned short*)d_ws;                      // 64 KB
    unsigned short* T   = (unsigned short*)d_ws + (size_t)IN_F * HID; // 25.6 MB
    // A_bf lives in d_out: [E][256] bf16 = 51.2 MB = exactly E*128 floats.
    // It is fully consumed by gemm_t before gather_sum overwrites d_out.
    unsigned short* Abf = (unsigned short*)d_out;

    conv_w_kernel<<<(IN_F * HID) / 256, 256, 0, stream>>>(W, Wt);
    conv_a_kernel<<<(E_EDGES * IN_F) / (256 * 8), 256, 0, stream>>>(edge_feats, Abf);
    gemm_t_kernel<<<(E_EDGES + 63) / 64, 256, 0, stream>>>(Abf, Wt, b, T);
    gather_sum_kernel<<<E_EDGES / 16, 256, 0, stream>>>(T, neighbors, out);
}

// Round 4
// 245.748 us; speedup vs baseline: 1.1048x; 1.0754x over previous
//
#include <hip/hip_runtime.h>
#include <hip/hip_bf16.h>
#include <stdint.h>

#define E_EDGES 100000
#define IN_F    256
#define HID     128
#define KNB     16

typedef short bf16x8 __attribute__((ext_vector_type(8)));
typedef float f32x4  __attribute__((ext_vector_type(4)));

__device__ __forceinline__ unsigned short f2bf(float f) {
    union { float f; unsigned u; } v; v.f = f;
    unsigned u = v.u;
    u += 0x7fffu + ((u >> 16) & 1u);   // round-to-nearest-even
    return (unsigned short)(u >> 16);
}

// W [256][128] fp32  ->  Wt [128][256] bf16 (transposed: [n][k])
__global__ void conv_w_kernel(const float* __restrict__ W, unsigned short* __restrict__ Wt) {
    int t = blockIdx.x * blockDim.x + threadIdx.x;   // 0..32767
    int n = t & (HID - 1);
    int k = t >> 7;
    Wt[(size_t)n * IN_F + k] = f2bf(W[(size_t)k * HID + n]);
}

// T = A @ W + b (A fp32, converted in-reg), stored bf16 [E][128].
// Block = 256 thr = 4 waves; block tile 64 rows x 128 cols; wave = 16 rows x 128 cols.
// All 16 fp32 A-loads issue BEFORE the barrier (pinned — can't sink past s_barrier,
// which was R2's failure mode). Wt staged once per block into LDS in MFMA-fragment
// order -> K-loop B-reads are stride-1 ds_read_b128, conflict-free.
__launch_bounds__(256)
__global__ void gemm_t_kernel(const float* __restrict__ A,
                              const unsigned short* __restrict__ Wt,
                              const float* __restrict__ bias,
                              unsigned short* __restrict__ T) {
    __shared__ unsigned short Bs[32768];   // 64 KB
    const int tid  = threadIdx.x;
    const int wave = tid >> 6;
    const int lane = tid & 63;
    const int l15  = lane & 15;
    const int quad = lane >> 4;
    const int rowbase = blockIdx.x * 64 + wave * 16;
    int arow = rowbase + l15;
    if (arow >= E_EDGES) arow = E_EDGES - 1;   // clamp; stores guarded below

    // Full-K fp32 A prefetch: 16 float4, all in flight before the barrier.
    const float* ap = A + (size_t)arow * IN_F + quad * 8;
    float4 af32[16];
    #pragma unroll
    for (int k0 = 0; k0 < 8; ++k0) {
        af32[2 * k0]     = *(const float4*)(ap + k0 * 32);
        af32[2 * k0 + 1] = *(const float4*)(ap + k0 * 32 + 4);
    }

    // Stage Wt -> LDS, swizzled to fragment order.
    // Source uint4 index e over Wt[128][256]: n=e>>5, k8=e&31 (k=k8*8).
    // Frag coords: k0=k8>>2, quad=k8&3, ct=n>>4, l15=n&15, lane=quad*16+l15.
    #pragma unroll
    for (int it = 0; it < 16; ++it) {
        int e    = it * 256 + tid;
        int n    = e >> 5;
        int k8   = e & 31;
        int dst  = ((k8 >> 2) * 8 + (n >> 4)) * 64 + (k8 & 3) * 16 + (n & 15);
        uint4 v = *(const uint4*)(Wt + (size_t)e * 8);
        *(uint4*)(Bs + (size_t)dst * 8) = v;
    }
    __syncthreads();

    // Convert prefetched A to bf16 fragments.
    bf16x8 apre[8];
    #pragma unroll
    for (int k0 = 0; k0 < 8; ++k0) {
        float4 lo = af32[2 * k0], hi = af32[2 * k0 + 1];
        bf16x8 f;
        f[0] = (short)f2bf(lo.x); f[1] = (short)f2bf(lo.y);
        f[2] = (short)f2bf(lo.z); f[3] = (short)f2bf(lo.w);
        f[4] = (short)f2bf(hi.x); f[5] = (short)f2bf(hi.y);
        f[6] = (short)f2bf(hi.z); f[7] = (short)f2bf(hi.w);
        apre[k0] = f;
    }

    f32x4 acc[8] = {};
    #pragma unroll
    for (int k0 = 0; k0 < 8; ++k0) {
        #pragma unroll
        for (int ct = 0; ct < 8; ++ct) {
            bf16x8 bf = *(const bf16x8*)(Bs + ((size_t)((k0 * 8 + ct) * 64 + lane)) * 8);
            acc[ct] = __builtin_amdgcn_mfma_f32_16x16x32_bf16(apre[k0], bf, acc[ct], 0, 0, 0);
        }
    }

    // Epilogue: +bias, bf16 store. C/D layout: col = l15, row = quad*4 + reg.
    #pragma unroll
    for (int ct = 0; ct < 8; ++ct) {
        const int col = ct * 16 + l15;
        const float bv = bias[col];
        #pragma unroll
        for (int i = 0; i < 4; ++i) {
            const int row = rowbase + quad * 4 + i;
            if (row < E_EDGES)
                T[(size_t)row * HID + col] = f2bf(acc[ct][i] + bv);
        }
    }
}

// out[i] = t[i] + sum_k t[nbr[i][k]]  (fp32 accumulate from bf16 t)
// Block = 256 thr = 16 edges; 16 lanes/edge, 8 feats/lane via uint4 (8 bf16).
// out stores are non-temporal so the 51.2 MB write stream doesn't evict hot T
// lines from L2.
__launch_bounds__(256)
__global__ void gather_sum_kernel(const unsigned short* __restrict__ T,
                                  const int* __restrict__ nbr,
                                  float* __restrict__ out) {
    __shared__ int sidx[256];
    const int tid   = threadIdx.x;
    const int edge0 = blockIdx.x * 16;
    sidx[tid] = nbr[(size_t)edge0 * KNB + tid];   // 16 edges x 16 nbrs
    __syncthreads();

    const int el   = tid >> 4;        // local edge 0..15
    const int lane = tid & 15;        // feature group: feats [lane*8, lane*8+8)
    const int edge = edge0 + el;

    float acc[8];
    {   // self row initializes acc
        uint4 v = *(const uint4*)(T + (size_t)edge * HID + lane * 8);
        unsigned w[4] = { v.x, v.y, v.z, v.w };
        union { unsigned u; float f; } c;
        #pragma unroll
        for (int j = 0; j < 4; ++j) {
            c.u = w[j] << 16;          acc[2 * j]     = c.f;
            c.u = w[j] & 0xffff0000u;  acc[2 * j + 1] = c.f;
        }
    }
    #pragma unroll
    for (int k = 0; k < KNB; ++k) {
        const int n = sidx[el * KNB + k];
        uint4 v = *(const uint4*)(T + (size_t)n * HID + lane * 8);
        unsigned w[4] = { v.x, v.y, v.z, v.w };
        union { unsigned u; float f; } c;
        #pragma unroll
        for (int j = 0; j < 4; ++j) {
            c.u = w[j] << 16;          acc[2 * j]     += c.f;
            c.u = w[j] & 0xffff0000u;  acc[2 * j + 1] += c.f;
        }
    }

    float* op = out + (size_t)edge * HID + lane * 8;
    f32x4 o0 = { acc[0], acc[1], acc[2], acc[3] };
    f32x4 o1 = { acc[4], acc[5], acc[6], acc[7] };
    __builtin_nontemporal_store(o0, (f32x4*)op);
    __builtin_nontemporal_store(o1, (f32x4*)(op + 4));
}

extern "C" void kernel_launch(void* const* d_in, const int* in_sizes, int n_in,
                              void* d_out, int out_size, void* d_ws, size_t ws_size,
                              hipStream_t stream) {
    const float* edge_feats = (const float*)d_in[0];   // [E, 256] fp32
    const int*   neighbors  = (const int*)d_in[1];     // [E, 16] int32
    const float* W          = (const float*)d_in[2];   // [256, 128] fp32
    const float* b          = (const float*)d_in[3];   // [128] fp32
    float*       out        = (float*)d_out;           // [E, 128] fp32

    unsigned short* Wt = (unsigned short*)d_ws;                      // 64 KB
    unsigned short* T  = (unsigned short*)d_ws + (size_t)IN_F * HID; // 25.6 MB

    conv_w_kernel<<<(IN_F * HID) / 256, 256, 0, stream>>>(W, Wt);
    gemm_t_kernel<<<(E_EDGES + 63) / 64, 256, 0, stream>>>(edge_feats, Wt, b, T);
    gather_sum_kernel<<<E_EDGES / 16, 256, 0, stream>>>(T, neighbors, out);
}